// Round 4
// baseline (126.612 us; speedup 1.0000x reference)
//
#include <hip/hip_runtime.h>

#define N_PTS 20000
#define CIN   32
#define COUT  64
#define KK    4
#define KF    64
#define KDIM  2048          // KF*CIN
#define E_PAD 262144
#define EPS   1e-12f
#define FOUR_OVER_PI 1.27323954473516f
#define QB    8             // queries per block (fallback kernel)
#define MT    32            // M-tile (gemm)

typedef __attribute__((ext_vector_type(8))) short bf16x8;
typedef __attribute__((ext_vector_type(4))) float f32x4;

__device__ __forceinline__ float sgnf(float v) {
    return v > 0.f ? 1.f : (v < 0.f ? -1.f : 0.f);
}
__device__ __forceinline__ int imin(int a, int b) { return a < b ? a : b; }
__device__ __forceinline__ int imax(int a, int b) { return a > b ? a : b; }

__device__ __forceinline__ unsigned short f2bf(float f) {   // RNE f32->bf16
    unsigned u = __float_as_uint(f);
    u = u + 0x7fffu + ((u >> 16) & 1u);
    return (unsigned short)(u >> 16);
}

// ball_to_cube_volume_preserving + trilinear cell (f32, op-for-op vs ref).
__device__ __forceinline__ void edge_geom(
    const float* __restrict__ pos, int n, int q,
    int& cellb, float& ofx, float& ofy, float& ofz)
{
    const float rx = (pos[n * 3 + 0] - pos[q * 3 + 0]) * 20.f;
    const float ry = (pos[n * 3 + 1] - pos[q * 3 + 1]) * 20.f;
    const float rz = (pos[n * 3 + 2] - pos[q * 3 + 2]) * 20.f;
    const float sq   = rx * rx + ry * ry + rz * rz;
    const float nrm  = sqrtf(fmaxf(sq, EPS));
    const float rxy2 = rx * rx + ry * ry;
    const bool  top  = (1.25f * rz * rz > rxy2);
    const float s_top  = sqrtf(fmaxf(3.f * nrm / (nrm + fabsf(rz) + EPS), EPS));
    const float s_side = nrm / sqrtf(fmaxf(rxy2, EPS));
    float cx = top ? rx * s_top : rx * s_side;
    float cy = top ? ry * s_top : ry * s_side;
    float cz = top ? sgnf(rz) * nrm : 1.5f * rz;
    if (sq < EPS) { cx = 0.f; cy = 0.f; cz = 0.f; }
    const float rc2 = cx * cx + cy * cy;
    const float rxy = sqrtf(fmaxf(rc2, EPS));
    const bool  xbig = fabsf(cy) <= fabsf(cx);
    const float safe_x = (fabsf(cx) > EPS) ? cx : 1.f;
    const float safe_y = (fabsf(cy) > EPS) ? cy : 1.f;
    const float qxv = sgnf(cx) * rxy;
    const float qyv = sgnf(cy) * rxy;
    float bx = xbig ? qxv : qyv * FOUR_OVER_PI * atanf(cx / safe_y);
    float by = xbig ? qxv * FOUR_OVER_PI * atanf(cy / safe_x) : qyv;
    if (rc2 < EPS) { bx = 0.f; by = 0.f; }
    const float ux = fminf(fmaxf((bx + 1.f) * 0.5f * 3.f, 0.f), 3.f);
    const float uy = fminf(fmaxf((by + 1.f) * 0.5f * 3.f, 0.f), 3.f);
    const float uz = fminf(fmaxf((cz + 1.f) * 0.5f * 3.f, 0.f), 3.f);
    const int ix = imin(imax((int)floorf(ux), 0), 2);
    const int iy = imin(imax((int)floorf(uy), 0), 2);
    const int iz = imin(imax((int)floorf(uz), 0), 2);
    cellb = (iz * KK + iy) * KK + ix;
    ofx = ux - (float)ix; ofy = uy - (float)iy; ofz = uz - (float)iz;
}

// CSR offsets from sorted edge_q (padding keyed to N_PTS).
__global__ __launch_bounds__(256) void build_qstart_kernel(
    const int* __restrict__ eq, const float* __restrict__ ev,
    int stride, int* __restrict__ qstart)
{
    int e = blockIdx.x * 256 + threadIdx.x;
    if (e >= E_PAD) return;
    int k = (ev[e] > 0.f) ? eq[e * stride] : N_PTS;
    if (k > N_PTS) k = N_PTS;
    int kp = -1;
    if (e > 0) {
        kp = (ev[e - 1] > 0.f) ? eq[(e - 1) * stride] : N_PTS;
        if (kp > N_PTS) kp = N_PTS;
    }
    for (int q = kp + 1; q <= k; ++q) qstart[q] = e;
    if (e == E_PAD - 1) {
        for (int q = k + 1; q <= N_PTS; ++q) qstart[q] = E_PAD;
    }
}

// Per-edge geometry to global records (edge-parallel, coalesced).
__global__ __launch_bounds__(256) void geom_kernel(
    const float* __restrict__ pos,
    const int* __restrict__ eq, const int* __restrict__ en,
    int strideQ, int strideN,
    int2* __restrict__ rec_m, float4* __restrict__ rec_f)
{
    const int e = blockIdx.x * 256 + threadIdx.x;
    if (e >= E_PAD) return;
    const int q = eq[e * strideQ];
    const int n = en[e * strideN];
    int ib; float fx, fy, fz;
    edge_geom(pos, n, q, ib, fx, fy, fz);
    rec_m[e] = make_int2(n, ib);
    rec_f[e] = make_float4(fx, fy, fz, 0.f);
}

// W[2048][64] f32 -> bf16 in B-fragment order: Wfrag[ks][nf][lane][j].
__global__ __launch_bounds__(256) void reorder_w_kernel(
    const float* __restrict__ Wconv, unsigned short* __restrict__ Wfrag)
{
    const int idx = blockIdx.x * 256 + threadIdx.x;   // 131072 total
    const int j    = idx & 7;
    const int lane = (idx >> 3) & 63;
    const int nf   = (idx >> 9) & 3;
    const int ks   = idx >> 11;
    const int k    = ks * 32 + ((lane >> 4) << 3) + j;
    const int col  = nf * 16 + (lane & 15);
    Wfrag[idx] = f2bf(Wconv[k * COUT + col]);
}

// Scatter: ONE WAVE PER QUERY, Z in registers. lane = cell (64 cells),
// each lane accumulates its cell's 32 channels in 32 VGPRs (static idx).
// No LDS, no RMW chain; rec + feats loads are uniform-address (broadcast).
__global__ __launch_bounds__(256, 8) void scatter_reg_kernel(
    const float* __restrict__ feats,
    const int2* __restrict__ rec_m, const float4* __restrict__ rec_f,
    const int* __restrict__ qstart, unsigned short* __restrict__ Zb)
{
    const int wave = threadIdx.x >> 6;
    const int lane = threadIdx.x & 63;
    const int q    = blockIdx.x * 4 + wave;

    const int ixc = lane & 3, iyc = (lane >> 2) & 3, izc = lane >> 4;

    float z[CIN];
    #pragma unroll
    for (int i = 0; i < CIN; ++i) z[i] = 0.f;

    const int lo = qstart[q], hi = qstart[q + 1];
    for (int e = lo; e < hi; ++e) {
        const int2   m = rec_m[e];
        const float4 f = rec_f[e];
        const int n = m.x, ib = m.y;
        const int ix = ib & 3, iy = (ib >> 2) & 3, iz = ib >> 4;
        const float wx = (ixc == ix) ? (1.f - f.x) : ((ixc == ix + 1) ? f.x : 0.f);
        const float wy = (iyc == iy) ? (1.f - f.y) : ((iyc == iy + 1) ? f.y : 0.f);
        const float wz = (izc == iz) ? (1.f - f.z) : ((izc == iz + 1) ? f.z : 0.f);
        const float w = wx * wy * wz;
        const float4* fr = (const float4*)(feats + (size_t)n * CIN);
        #pragma unroll
        for (int c4 = 0; c4 < CIN / 4; ++c4) {
            const float4 f4 = fr[c4];            // same addr all lanes (L1/L2 bcast)
            z[c4 * 4 + 0] += w * f4.x;
            z[c4 * 4 + 1] += w * f4.y;
            z[c4 * 4 + 2] += w * f4.z;
            z[c4 * 4 + 3] += w * f4.w;
        }
    }

    // pack to bf16, write 64B per lane: Zb[q][k], k = lane*32 + ci.
    unsigned p[CIN / 2];
    #pragma unroll
    for (int i = 0; i < CIN / 2; ++i)
        p[i] = (unsigned)f2bf(z[2 * i]) | ((unsigned)f2bf(z[2 * i + 1]) << 16);
    uint4* dst = (uint4*)(Zb + (size_t)q * KDIM + lane * CIN);
    #pragma unroll
    for (int i = 0; i < 4; ++i) {
        uint4 v; v.x = p[4 * i]; v.y = p[4 * i + 1];
        v.z = p[4 * i + 2]; v.w = p[4 * i + 3];
        dst[i] = v;
    }
}

// GEMM: out[20000][64] = Zb[20000][2048] x W[2048][64] (bf16 MFMA, f32 acc),
// plus the dense head in the epilogue. 4 waves split K; LDS reduce.
__global__ __launch_bounds__(256) void gemm_kernel(
    const unsigned short* __restrict__ Zb, const unsigned short* __restrict__ Wfrag,
    const float* __restrict__ feats, const float* __restrict__ Wd,
    const float* __restrict__ bd, float* __restrict__ out)
{
    __shared__ float red[4][MT][COUT + 2];

    const int t    = threadIdx.x;
    const int wave = t >> 6;
    const int lane = t & 63;
    const int m0   = blockIdx.x * MT;
    const int r16  = lane & 15;
    const int kgrp = lane >> 4;

    f32x4 acc[2][4];
    #pragma unroll
    for (int mi = 0; mi < 2; ++mi)
        #pragma unroll
        for (int nf = 0; nf < 4; ++nf)
            acc[mi][nf] = (f32x4){0.f, 0.f, 0.f, 0.f};

    for (int ks16 = 0; ks16 < 16; ++ks16) {
        const int ks   = wave * 16 + ks16;
        const int koff = ks * 32 + kgrp * 8;
        bf16x8 af[2], bfg[4];
        #pragma unroll
        for (int mi = 0; mi < 2; ++mi)
            af[mi] = *(const bf16x8*)(Zb + (size_t)(m0 + mi * 16 + r16) * KDIM + koff);
        #pragma unroll
        for (int nf = 0; nf < 4; ++nf)
            bfg[nf] = *(const bf16x8*)(Wfrag + (((ks * 4 + nf) * 64) + lane) * 8);
        #pragma unroll
        for (int mi = 0; mi < 2; ++mi)
            #pragma unroll
            for (int nf = 0; nf < 4; ++nf)
                acc[mi][nf] = __builtin_amdgcn_mfma_f32_16x16x32_bf16(
                    af[mi], bfg[nf], acc[mi][nf], 0, 0, 0);
    }

    #pragma unroll
    for (int mi = 0; mi < 2; ++mi)
        #pragma unroll
        for (int nf = 0; nf < 4; ++nf)
            #pragma unroll
            for (int rg = 0; rg < 4; ++rg)
                red[wave][mi * 16 + kgrp * 4 + rg][nf * 16 + r16] = acc[mi][nf][rg];
    __syncthreads();

    for (int idx = t; idx < MT * COUT; idx += 256) {
        const int r = idx >> 6, o = idx & 63;
        const int q = m0 + r;
        out[q * COUT + o] =
            red[0][r][o] + red[1][r][o] + red[2][r][o] + red[3][r][o];
        float dacc = bd[o];
        #pragma unroll
        for (int i = 0; i < CIN; ++i)
            dacc += feats[q * CIN + i] * Wd[i * COUT + o];
        out[N_PTS * COUT + q * COUT + o] = dacc;
    }
}

// ---------------- Fallback (round-2 monolithic) if ws too small ----------
__global__ __launch_bounds__(256) void conv_dense_kernel(
    const float* __restrict__ feats, const float* __restrict__ pos,
    const float* __restrict__ Wconv, const float* __restrict__ Wd,
    const float* __restrict__ bd,
    const int* __restrict__ en, const float* __restrict__ ev,
    const int* __restrict__ qstart, int strideN,
    float* __restrict__ out)
{
    __shared__ float Z[QB][KF][CIN];
    __shared__ float partial[4][QB][COUT];
    __shared__ int   rec_n[256], rec_b[256];
    __shared__ float rec_fx[256], rec_fy[256], rec_fz[256];
    __shared__ int   qs9[QB + 1];

    const int t = threadIdx.x, wave = t >> 6, lane = t & 63;
    const int q0 = blockIdx.x * QB;
    if (t <= QB) qs9[t] = qstart[q0 + t];
    float* zf = &Z[0][0][0];
    for (int j = t; j < QB * KF * CIN; j += 256) zf[j] = 0.f;
    __syncthreads();
    const int eLo = qs9[0], eHi = qs9[QB];
    const int ci = lane & 31, dbase = lane >> 5;
    for (int cb = eLo; cb < eHi; cb += 256) {
        const int cnt = imin(256, eHi - cb);
        if (t < cnt) {
            const int e = cb + t;
            int q = q0;
            #pragma unroll
            for (int s = 1; s < QB; ++s) if (e >= qs9[s]) q = q0 + s;
            const int n = en[e * strideN];
            int ib; float fx, fy, fz;
            edge_geom(pos, n, q, ib, fx, fy, fz);
            rec_n[t] = n; rec_b[t] = ib;
            rec_fx[t] = fx; rec_fy[t] = fy; rec_fz[t] = fz;
        }
        __syncthreads();
        for (int s = 0; s < QB / 4; ++s) {
            const int qs = wave * (QB / 4) + s;
            const int lo = imax(qs9[qs], cb);
            const int hi = imin(qs9[qs + 1], cb + cnt);
            for (int e = lo; e < hi; ++e) {
                const int r = e - cb;
                const int n = rec_n[r], ib = rec_b[r];
                const float fx = rec_fx[r], fy = rec_fy[r], fz = rec_fz[r];
                const float fj = feats[n * CIN + ci];
                const float wxf = dbase ? fx : 1.f - fx;
                #pragma unroll
                for (int dd = 0; dd < 4; ++dd) {
                    const int dy = dd & 1, dz = dd >> 1;
                    const float w = (dz ? fz : 1.f - fz) * (dy ? fy : 1.f - fy) * wxf;
                    Z[qs][ib + dz * 16 + dy * 4 + dbase][ci] += fj * w;
                }
            }
        }
        __syncthreads();
    }
    float acc[QB];
    #pragma unroll
    for (int qs = 0; qs < QB; ++qs) acc[qs] = 0.f;
    const int o = lane;
    for (int kk = 0; kk < KF / 4; ++kk) {
        const int kf = wave * (KF / 4) + kk;
        #pragma unroll
        for (int ii = 0; ii < CIN; ii += 4) {
            float4 z4[QB];
            #pragma unroll
            for (int qs = 0; qs < QB; ++qs)
                z4[qs] = *(const float4*)&Z[qs][kf][ii];
            #pragma unroll
            for (int c = 0; c < 4; ++c) {
                const float wv = Wconv[(kf * CIN + ii + c) * COUT + o];
                #pragma unroll
                for (int qs = 0; qs < QB; ++qs)
                    acc[qs] += wv * ((const float*)&z4[qs])[c];
            }
        }
    }
    #pragma unroll
    for (int qs = 0; qs < QB; ++qs) partial[wave][qs][o] = acc[qs];
    __syncthreads();
    for (int s = 0; s < QB / 4; ++s) {
        const int qs = wave * (QB / 4) + s;
        const int q  = q0 + qs;
        out[q * COUT + o] = partial[0][qs][o] + partial[1][qs][o] +
                            partial[2][qs][o] + partial[3][qs][o];
        float dacc = bd[o];
        #pragma unroll
        for (int ii = 0; ii < CIN; ++ii)
            dacc += feats[q * CIN + ii] * Wd[ii * COUT + o];
        out[N_PTS * COUT + q * COUT + o] = dacc;
    }
}

extern "C" void kernel_launch(void* const* d_in, const int* in_sizes, int n_in,
                              void* d_out, int out_size, void* d_ws, size_t ws_size,
                              hipStream_t stream)
{
    const float* feats = (const float*)d_in[0];
    const float* pos   = (const float*)d_in[1];
    const float* Wconv = (const float*)d_in[2];
    const float* Wd    = (const float*)d_in[3];
    const float* bd    = (const float*)d_in[4];
    const int*   eq    = (const int*)d_in[5];
    const int*   en    = (const int*)d_in[6];
    const float* ev    = (const float*)d_in[7];
    const int strideQ = in_sizes[5] / E_PAD;   // int32 vs int64 hedge
    const int strideN = in_sizes[6] / E_PAD;

    int* qstart = (int*)d_ws;
    const size_t offW = 81920;                              // Wfrag (256 KB)
    const size_t offZ = offW + 262144;                      // Zb (81.92 MB)
    const size_t offM = offZ + (size_t)N_PTS * KDIM * 2;    // rec_m (2 MB)
    const size_t offF = offM + (size_t)E_PAD * 8;           // rec_f (4 MB)
    const size_t needed = offF + (size_t)E_PAD * 16;

    build_qstart_kernel<<<E_PAD / 256, 256, 0, stream>>>(eq, ev, strideQ, qstart);

    if (ws_size >= needed) {
        unsigned short* Wfrag = (unsigned short*)((char*)d_ws + offW);
        unsigned short* Zb    = (unsigned short*)((char*)d_ws + offZ);
        int2*   rec_m = (int2*)((char*)d_ws + offM);
        float4* rec_f = (float4*)((char*)d_ws + offF);
        reorder_w_kernel<<<KDIM * COUT / 256, 256, 0, stream>>>(Wconv, Wfrag);
        geom_kernel<<<E_PAD / 256, 256, 0, stream>>>(
            pos, eq, en, strideQ, strideN, rec_m, rec_f);
        scatter_reg_kernel<<<N_PTS / 4, 256, 0, stream>>>(
            feats, rec_m, rec_f, qstart, Zb);
        gemm_kernel<<<N_PTS / MT, 256, 0, stream>>>(
            Zb, Wfrag, feats, Wd, bd, (float*)d_out);
    } else {
        conv_dense_kernel<<<N_PTS / QB, 256, 0, stream>>>(
            feats, pos, Wconv, Wd, bd, en, ev, qstart, strideN, (float*)d_out);
    }
}